// Round 5
// baseline (282.935 us; speedup 1.0000x reference)
//
#include <hip/hip_runtime.h>
#include <math.h>

typedef unsigned short u16;
typedef __bf16 bf16x8 __attribute__((ext_vector_type(8)));
typedef float f32x4 __attribute__((ext_vector_type(4)));

__device__ __forceinline__ u16 f2bf(float f){
  union{float f; unsigned u;} v; v.f = f;
  return (u16)((v.u + 0x7fffu + ((v.u >> 16) & 1u)) >> 16);
}
__device__ __forceinline__ float bf2f(u16 b){
  union{unsigned u; float f;} v; v.u = (unsigned)b << 16; return v.f;
}

#define LOG2E 1.4426950408889634f

// ---------------------------------------------------------------------------
// transpose + cast + scale: fp32 [R][C] -> bf16 [C][R] * scale
__global__ void tpose_cast(u16* __restrict__ dst, const float* __restrict__ src,
                           int R, int C, float scale){
  __shared__ float t[32][33];
  int c0 = blockIdx.x * 32, r0 = blockIdx.y * 32;
  int tx = threadIdx.x, ty = threadIdx.y;
  #pragma unroll
  for (int i = 0; i < 4; i++)
    t[ty + i*8][tx] = src[(size_t)(r0 + ty + i*8) * C + c0 + tx];
  __syncthreads();
  #pragma unroll
  for (int i = 0; i < 4; i++)
    dst[(size_t)(c0 + ty + i*8) * R + r0 + tx] = f2bf(t[tx][ty + i*8] * scale);
}

// biasPb[b][q][kt][l15][fk] = bf16( (sp+ed)[b][q][kt*128 + fk*16 + l15] * log2e )
__global__ void bias_prep(u16* __restrict__ dst, const float* __restrict__ sp,
                          const float* __restrict__ ed){
  int t = blockIdx.x * blockDim.x + threadIdx.x;   // 16*512*128
  int row = t >> 7, c0 = (t & 127) * 4;
  size_t base = (size_t)row * 512;
  float4 s = *(const float4*)&sp[base + c0];
  float4 e = *(const float4*)&ed[base + c0];
  int kt = c0 >> 7, cw = c0 & 127, fk = cw >> 4, l0 = cw & 15;
  u16* o = dst + base + kt*128 + fk;
  o[(l0+0)*8] = f2bf((s.x+e.x)*LOG2E);
  o[(l0+1)*8] = f2bf((s.y+e.y)*LOG2E);
  o[(l0+2)*8] = f2bf((s.z+e.z)*LOG2E);
  o[(l0+3)*8] = f2bf((s.w+e.w)*LOG2E);
}

// qkvb[0:1536)=0, qkvb[1536+i]=bv[i]
__global__ void build_qkvb(float* __restrict__ qkvb, const float* __restrict__ bv){
  int i = blockIdx.x * blockDim.x + threadIdx.x;
  if (i < 2304) qkvb[i] = (i < 1536) ? 0.f : bv[i - 1536];
}

// ---------------------------------------------------------------------------
// LayerNorm: one wave per row, produce h1 (g1,be1) and h2 (g2,be2) in bf16
__global__ __launch_bounds__(256) void ln_kernel(
    const float* __restrict__ x,
    const float* __restrict__ g1, const float* __restrict__ be1,
    const float* __restrict__ g2, const float* __restrict__ be2,
    u16* __restrict__ h1, u16* __restrict__ h2){
  const int lane = threadIdx.x & 63, wave = threadIdx.x >> 6;
  const int row = blockIdx.x * 4 + wave;
  const float4* xr = (const float4*)(x + (size_t)row * 768);
  float4 v[3];
  float sum = 0.f, sq = 0.f;
  #pragma unroll
  for (int c = 0; c < 3; c++){
    v[c] = xr[lane + 64*c];
    sum += v[c].x + v[c].y + v[c].z + v[c].w;
    sq  += v[c].x*v[c].x + v[c].y*v[c].y + v[c].z*v[c].z + v[c].w*v[c].w;
  }
  #pragma unroll
  for (int d = 1; d < 64; d <<= 1){ sum += __shfl_xor(sum, d); sq += __shfl_xor(sq, d); }
  float mu  = sum * (1.f/768.f);
  float var = sq * (1.f/768.f) - mu*mu;
  float rs  = rsqrtf(var + 1e-5f);
  #pragma unroll
  for (int c = 0; c < 3; c++){
    int f4 = lane + 64*c;
    float4 ga = ((const float4*)g1)[f4], ba = ((const float4*)be1)[f4];
    float4 gb = ((const float4*)g2)[f4], bb = ((const float4*)be2)[f4];
    float nx = (v[c].x-mu)*rs, ny = (v[c].y-mu)*rs, nz = (v[c].z-mu)*rs, nw = (v[c].w-mu)*rs;
    ushort4 o1{f2bf(nx*ga.x+ba.x), f2bf(ny*ga.y+ba.y), f2bf(nz*ga.z+ba.z), f2bf(nw*ga.w+ba.w)};
    ushort4 o2{f2bf(nx*gb.x+bb.x), f2bf(ny*gb.y+bb.y), f2bf(nz*gb.z+bb.z), f2bf(nw*gb.w+bb.w)};
    ((ushort4*)(h1 + (size_t)row*768))[f4] = o1;
    ((ushort4*)(h2 + (size_t)row*768))[f4] = o2;
  }
}

// ---------------------------------------------------------------------------
// GEMM: C[M,N] = A[M,K](bf16) @ Bt[N,K](bf16)^T, fp32 accum.
// BK=64, XOR-swizzled LDS (inverse-swizzled global_load_lds source),
// XCD-aware block swizzle (grid %8==0), 2-phase double-buffered pipeline:
// one barrier per K-step, next tile's loads in flight during compute.
// EPI 0: +bias -> bf16            EPI 2: +bias, gelu -> bf16
// EPI 3: +bias +resid(f32) -> bf16   EPI 4: +bias +resid(bf16) -> f32
template<int EPI>
__global__ __launch_bounds__(256, 2) void gemm_bt(
    const u16* __restrict__ A, const u16* __restrict__ Bt, void* __restrict__ Cout,
    const float* __restrict__ bias, const void* __restrict__ resid,
    int M, int Nn, int K){
  __shared__ __align__(16) u16 As[2][128*64];
  __shared__ __align__(16) u16 Bs[2][128*64];
  const int tid = threadIdx.x, lane = tid & 63, wave = tid >> 6;
  const int wm = wave >> 1, wn = wave & 1;
  const int l15 = lane & 15, lg = lane >> 4;
  // XCD-aware swizzle: consecutive remapped blocks share the A-panel
  const int bid = blockIdx.y * gridDim.x + blockIdx.x;
  const int cpx = (gridDim.x * gridDim.y) >> 3;
  const int swz = (bid & 7) * cpx + (bid >> 3);
  const int m0 = (swz / gridDim.x) * 128, n0 = (swz % gridDim.x) * 128;

#define STAGE(buf, k0) do { \
    _Pragma("unroll") \
    for (int i_ = 0; i_ < 4; i_++){ \
      int chunk_ = i_*256 + tid; \
      int row_ = chunk_ >> 3, seg_ = (chunk_ & 7) ^ (row_ & 7); \
      __builtin_amdgcn_global_load_lds( \
        (const __attribute__((address_space(1))) void*)&A[(size_t)(m0+row_)*K + (k0) + seg_*8], \
        (__attribute__((address_space(3))) void*)&As[buf][(size_t)(i_*256 + wave*64)*8], 16, 0, 0); \
      __builtin_amdgcn_global_load_lds( \
        (const __attribute__((address_space(1))) void*)&Bt[(size_t)(n0+row_)*K + (k0) + seg_*8], \
        (__attribute__((address_space(3))) void*)&Bs[buf][(size_t)(i_*256 + wave*64)*8], 16, 0, 0); \
    } } while(0)

  f32x4 acc[4][4] = {};
  const int nt = K >> 6;
  STAGE(0, 0);
  int cur = 0;
  for (int t = 0; t < nt; t++){
    __syncthreads();                        // drains stage(cur); reuse-safe
    if (t + 1 < nt) STAGE(cur ^ 1, (t+1) << 6);   // prefetch next tile
    const u16* Ac = As[cur];
    const u16* Bc = Bs[cur];
    bf16x8 af[4][2], bfr[4][2];
    #pragma unroll
    for (int i = 0; i < 4; i++){
      int ra = wm*64 + i*16 + l15, rb = wn*64 + i*16 + l15;
      #pragma unroll
      for (int kk = 0; kk < 2; kk++){
        af[i][kk]  = *(const bf16x8*)&Ac[ra*64 + (((kk*4 + lg) ^ (l15 & 7)) << 3)];
        bfr[i][kk] = *(const bf16x8*)&Bc[rb*64 + (((kk*4 + lg) ^ (l15 & 7)) << 3)];
      }
    }
    #pragma unroll
    for (int kk = 0; kk < 2; kk++)
      #pragma unroll
      for (int i = 0; i < 4; i++)
        #pragma unroll
        for (int j = 0; j < 4; j++)
          acc[i][j] = __builtin_amdgcn_mfma_f32_16x16x32_bf16(af[i][kk], bfr[j][kk], acc[i][j], 0, 0, 0);
    cur ^= 1;
  }
#undef STAGE
  #pragma unroll
  for (int i = 0; i < 4; i++){
    int row_base = m0 + wm*64 + i*16 + lg*4;
    #pragma unroll
    for (int j = 0; j < 4; j++){
      int col = n0 + wn*64 + j*16 + l15;
      float bb = bias ? bias[col] : 0.f;
      #pragma unroll
      for (int r = 0; r < 4; r++){
        size_t idx = (size_t)(row_base + r) * Nn + col;
        float v = acc[i][j][r] + bb;
        if (EPI == 3){
          v += ((const float*)resid)[idx];
          ((u16*)Cout)[idx] = f2bf(v);
        } else if (EPI == 4){
          v += bf2f(((const u16*)resid)[idx]);
          ((float*)Cout)[idx] = v;
        } else if (EPI == 2){
          float u = v + 0.044715f * v * v * v;
          float e = exp2f(-2.3022182f * u);          // exp(-1.5957691*u)
          ((u16*)Cout)[idx] = f2bf(v * __builtin_amdgcn_rcpf(1.f + e));
        } else {
          ((u16*)Cout)[idx] = f2bf(v);
        }
      }
    }
  }
}

// ---------------------------------------------------------------------------
// qkv v-part -> VT [B,H,64,512] via LDS tile transpose.
// Column index XOR-swizzled within each 128-col tile (chunk ^= hd&7).
__global__ void vtrans(const u16* __restrict__ qkv, u16* __restrict__ VTg){
  __shared__ u16 t[32][33];
  int bh = blockIdx.z, b = bh / 12, h = bh % 12;
  int n0 = blockIdx.x * 32, hd0 = blockIdx.y * 32;
  int tx = threadIdx.x, ty = threadIdx.y;
  #pragma unroll
  for (int i = 0; i < 4; i++){
    int n = n0 + ty + i*8;
    t[ty + i*8][tx] = qkv[((size_t)(b*512 + n))*2304 + 1536 + h*64 + hd0 + tx];
  }
  __syncthreads();
  #pragma unroll
  for (int i = 0; i < 4; i++){
    int hd = hd0 + ty + i*8;
    int col = n0 + tx;
    int tile = col >> 7, within = col & 127;
    int newcol = (tile << 7) + ((((within >> 3) ^ (hd & 7)) << 3)) + (within & 7);
    VTg[((size_t)bh*64 + hd)*512 + newcol] = t[tx][ty + i*8];
  }
}

// ---------------------------------------------------------------------------
// Attention: block = (q-tile 128) x (b,h); 4 waves, each 32 q-rows.
// K/V LDS-staged per block per kt; bf16 bias; unshifted exp2 softmax.
__global__ __launch_bounds__(256, 2) void attn_kernel(
    const u16* __restrict__ qkv, const u16* __restrict__ VTg,
    const u16* __restrict__ biasPb, u16* __restrict__ Og){
  __shared__ __align__(16) u16 Ks[128*64];
  __shared__ __align__(16) u16 Vs[64*128];
  __shared__ __align__(16) u16 Pl[4*32*136];
  const int tid = threadIdx.x, lane = tid & 63, wave = tid >> 6;
  const int l15 = lane & 15, lg = lane >> 4;
  // XCD swizzle: 4 consecutive remapped blocks share (b,h) K/V
  const int bid = blockIdx.y * 4 + blockIdx.x;           // nwg = 768
  const int swz = (bid & 7) * 96 + (bid >> 3);
  const int bh = swz >> 2, b = bh / 12, h = bh % 12;
  const int q0 = (swz & 3) * 128 + wave * 32;
  const u16* Qb = qkv + (size_t)b * 512 * 2304 + h * 64;   // row stride 2304
  const u16* Kb = Qb + 768;
  const u16* Vbh = VTg + (size_t)bh * 64 * 512;
  u16* Pw = &Pl[wave * 32 * 136];

  bf16x8 qf[2][2];
  #pragma unroll
  for (int fm = 0; fm < 2; fm++)
    #pragma unroll
    for (int kk = 0; kk < 2; kk++)
      qf[fm][kk] = *(const bf16x8*)&Qb[(size_t)(q0 + fm*16 + l15)*2304 + kk*32 + lg*8];

  f32x4 O[2][4] = {};
  float lrow[2][4] = {};

  for (int kt = 0; kt < 4; kt++){
    const int k0 = kt * 128;
    // bias: one bf16x8 per (fm,r)
    bf16x8 bb[2][4];
    #pragma unroll
    for (int fm = 0; fm < 2; fm++)
      #pragma unroll
      for (int r = 0; r < 4; r++){
        int qrow = q0 + fm*16 + lg*4 + r;
        bb[fm][r] = *(const bf16x8*)&biasPb[((size_t)(b*512 + qrow)*4 + kt)*128 + l15*8];
      }
    // stage K tile [128][64] (inverse-swizzled source, linear dest)
    #pragma unroll
    for (int i = 0; i < 4; i++){
      int chunk = i*256 + tid;
      int r = chunk >> 3, cc = chunk & 7;
      __builtin_amdgcn_global_load_lds(
        (const __attribute__((address_space(1))) void*)&Kb[(size_t)(k0 + r)*2304 + ((cc ^ (r & 7)) << 3)],
        (__attribute__((address_space(3))) void*)&Ks[(size_t)(i*256 + wave*64)*8],
        16, 0, 0);
    }
    // stage V tile [64][128] from pre-swizzled VTg (linear copy)
    #pragma unroll
    for (int i = 0; i < 4; i++){
      int chunk = i*256 + tid;
      int r = chunk >> 4, cc = chunk & 15;
      __builtin_amdgcn_global_load_lds(
        (const __attribute__((address_space(1))) void*)&Vbh[(size_t)r*512 + k0 + (cc << 3)],
        (__attribute__((address_space(3))) void*)&Vs[(size_t)(i*256 + wave*64)*8],
        16, 0, 0);
    }
    __syncthreads();

    // QK^T from LDS (swizzled reads)
    f32x4 S[2][8] = {};
    #pragma unroll
    for (int fk = 0; fk < 8; fk++)
      #pragma unroll
      for (int kk = 0; kk < 2; kk++){
        int row = fk*16 + l15;
        bf16x8 kf = *(const bf16x8*)&Ks[row*64 + (((kk*4 + lg) ^ (l15 & 7)) << 3)];
        S[0][fk] = __builtin_amdgcn_mfma_f32_16x16x32_bf16(qf[0][kk], kf, S[0][fk], 0,0,0);
        S[1][fk] = __builtin_amdgcn_mfma_f32_16x16x32_bf16(qf[1][kk], kf, S[1][fk], 0,0,0);
      }
    // p = exp2(qk' + bias'); row sums (no shift needed: args bounded, f32 accum)
    #pragma unroll
    for (int fm = 0; fm < 2; fm++)
      #pragma unroll
      for (int r = 0; r < 4; r++){
        float rs = 0.f;
        #pragma unroll
        for (int fk = 0; fk < 8; fk++){
          float p = exp2f(S[fm][fk][r] + (float)bb[fm][r][fk]);
          S[fm][fk][r] = p;
          rs += p;
        }
        rs += __shfl_xor(rs, 1); rs += __shfl_xor(rs, 2);
        rs += __shfl_xor(rs, 4); rs += __shfl_xor(rs, 8);
        lrow[fm][r] += rs;
      }
    // P -> LDS (per-wave private; intra-wave ordering, no extra barrier)
    #pragma unroll
    for (int fm = 0; fm < 2; fm++)
      #pragma unroll
      for (int fk = 0; fk < 8; fk++)
        #pragma unroll
        for (int r = 0; r < 4; r++)
          Pw[(fm*16 + lg*4 + r)*136 + fk*16 + l15] = f2bf(S[fm][fk][r]);
    bf16x8 pf[2][4];
    #pragma unroll
    for (int fm = 0; fm < 2; fm++)
      #pragma unroll
      for (int kk = 0; kk < 4; kk++)
        pf[fm][kk] = *(const bf16x8*)&Pw[(fm*16 + l15)*136 + kk*32 + lg*8];
    // PV from LDS V (swizzled reads)
    #pragma unroll
    for (int fn = 0; fn < 4; fn++)
      #pragma unroll
      for (int kk = 0; kk < 4; kk++){
        int row = fn*16 + l15;
        bf16x8 vf = *(const bf16x8*)&Vs[row*128 + (((kk*4 + lg) ^ (l15 & 7)) << 3)];
        O[0][fn] = __builtin_amdgcn_mfma_f32_16x16x32_bf16(pf[0][kk], vf, O[0][fn], 0,0,0);
        O[1][fn] = __builtin_amdgcn_mfma_f32_16x16x32_bf16(pf[1][kk], vf, O[1][fn], 0,0,0);
      }
    __syncthreads();   // all waves done with Ks/Vs before next stage
  }
  #pragma unroll
  for (int fm = 0; fm < 2; fm++)
    #pragma unroll
    for (int r = 0; r < 4; r++){
      float inv = __builtin_amdgcn_rcpf(lrow[fm][r]);
      int qrow = q0 + fm*16 + lg*4 + r;
      #pragma unroll
      for (int fn = 0; fn < 4; fn++)
        Og[((size_t)b*512 + qrow)*768 + h*64 + fn*16 + l15] = f2bf(O[fm][fn][r] * inv);
    }
}

// ---------------------------------------------------------------------------
extern "C" void kernel_launch(void* const* d_in, const int* in_sizes, int n_in,
                              void* d_out, int out_size, void* d_ws, size_t ws_size,
                              hipStream_t stream){
  const float* x   = (const float*)d_in[0];
  const float* sp  = (const float*)d_in[1];
  const float* ed  = (const float*)d_in[2];
  const float* Wq  = (const float*)d_in[3];
  const float* Wk  = (const float*)d_in[4];
  const float* Wv  = (const float*)d_in[5];
  const float* bv  = (const float*)d_in[6];
  const float* Wo  = (const float*)d_in[7];
  const float* bo  = (const float*)d_in[8];
  const float* g1  = (const float*)d_in[9];
  const float* be1 = (const float*)d_in[10];
  const float* g2  = (const float*)d_in[11];
  const float* be2 = (const float*)d_in[12];
  const float* W1  = (const float*)d_in[13];
  const float* bf1 = (const float*)d_in[14];
  const float* W2  = (const float*)d_in[15];
  const float* bf2 = (const float*)d_in[16];

  char* w = (char*)d_ws;
  size_t off = 0;
  auto alloc = [&](size_t bytes)->void*{ void* p = w + off; off += (bytes + 255) & ~(size_t)255; return p; };
  u16*   Gg    = (u16*)  alloc(8192ull*3072*2);   // FFN1 out; first 37.7MB double as qkv
  u16*   qkv   = Gg;                               // [8192][2304] bf16 (dead before FFN1)
  u16*   VTg   = (u16*)  alloc(8192ull*768*2);
  u16*   h1    = (u16*)  alloc(8192ull*768*2);
  u16*   h2    = (u16*)  alloc(8192ull*768*2);
  u16*   Og    = (u16*)  alloc(8192ull*768*2);
  u16*   attb  = (u16*)  alloc(8192ull*768*2);    // bf16 att residual
  u16*   biasPb= (u16*)  alloc(16ull*512*512*2);
  u16*   WqkvT = (u16*)  alloc(2304ull*768*2);
  u16*   WoT   = (u16*)  alloc(768ull*768*2);
  u16*   W1T   = (u16*)  alloc(3072ull*768*2);
  u16*   W2T   = (u16*)  alloc(768ull*3072*2);
  float* qkvb  = (float*)alloc(2304ull*4);

  const float qscale = 0.03608439182435161f * LOG2E;  // D^-0.5 * log2e folded into Wq

  // --- prep ---
  tpose_cast<<<dim3(24,24),dim3(32,8),0,stream>>>(WqkvT,            Wq, 768, 768, qscale);
  tpose_cast<<<dim3(24,24),dim3(32,8),0,stream>>>(WqkvT + 768*768,  Wk, 768, 768, 1.f);
  tpose_cast<<<dim3(24,24),dim3(32,8),0,stream>>>(WqkvT + 1536*768, Wv, 768, 768, 1.f);
  tpose_cast<<<dim3(24,24),dim3(32,8),0,stream>>>(WoT,              Wo, 768, 768, 1.f);
  tpose_cast<<<dim3(96,24),dim3(32,8),0,stream>>>(W1T, W1, 768, 3072, 1.f);
  tpose_cast<<<dim3(24,96),dim3(32,8),0,stream>>>(W2T, W2, 3072, 768, 1.f);
  bias_prep<<<4096,256,0,stream>>>(biasPb, sp, ed);
  build_qkvb<<<9,256,0,stream>>>(qkvb, bv);

  // --- layer norms (shared stats) ---
  ln_kernel<<<2048,256,0,stream>>>(x, g1, be1, g2, be2, h1, h2);

  // --- qkv projection ---
  gemm_bt<0><<<dim3(18,64),256,0,stream>>>(h1, WqkvT, qkv, qkvb, nullptr, 8192, 2304, 768);
  vtrans<<<dim3(16,2,192),dim3(32,8),0,stream>>>(qkv, VTg);

  // --- attention ---
  attn_kernel<<<dim3(4,192),256,0,stream>>>(qkv, VTg, biasPb, Og);

  // --- output projection + residual x -> bf16 att ---
  gemm_bt<3><<<dim3(6,64),256,0,stream>>>(Og, WoT, attb, bo, x, 8192, 768, 768);

  // --- FFN ---
  gemm_bt<2><<<dim3(24,64),256,0,stream>>>(h2, W1T, Gg, bf1, nullptr, 8192, 3072, 768);
  gemm_bt<4><<<dim3(6,64),256,0,stream>>>(Gg, W2T, (float*)d_out, bf2, attb, 8192, 768, 3072);
}

// Round 6
// 263.547 us; speedup vs baseline: 1.0736x; 1.0736x over previous
//
#include <hip/hip_runtime.h>
#include <math.h>

typedef unsigned short u16;
typedef __bf16 bf16x8 __attribute__((ext_vector_type(8)));
typedef float f32x4 __attribute__((ext_vector_type(4)));

__device__ __forceinline__ u16 f2bf(float f){
  union{float f; unsigned u;} v; v.f = f;
  return (u16)((v.u + 0x7fffu + ((v.u >> 16) & 1u)) >> 16);
}
__device__ __forceinline__ float bf2f(u16 b){
  union{unsigned u; float f;} v; v.u = (unsigned)b << 16; return v.f;
}

#define LOG2E 1.4426950408889634f

// ---------------------------------------------------------------------------
// transpose + cast + scale: fp32 [R][C] -> bf16 [C][R] * scale
__global__ void tpose_cast(u16* __restrict__ dst, const float* __restrict__ src,
                           int R, int C, float scale){
  __shared__ float t[32][33];
  int c0 = blockIdx.x * 32, r0 = blockIdx.y * 32;
  int tx = threadIdx.x, ty = threadIdx.y;
  #pragma unroll
  for (int i = 0; i < 4; i++)
    t[ty + i*8][tx] = src[(size_t)(r0 + ty + i*8) * C + c0 + tx];
  __syncthreads();
  #pragma unroll
  for (int i = 0; i < 4; i++)
    dst[(size_t)(c0 + ty + i*8) * R + r0 + tx] = f2bf(t[tx][ty + i*8] * scale);
}

// biasPb[b][q][kt][l15][fk] = bf16( (sp+ed)[b][q][kt*128 + fk*16 + l15] * log2e )
__global__ void bias_prep(u16* __restrict__ dst, const float* __restrict__ sp,
                          const float* __restrict__ ed){
  int t = blockIdx.x * blockDim.x + threadIdx.x;   // 16*512*128
  int row = t >> 7, c0 = (t & 127) * 4;
  size_t base = (size_t)row * 512;
  float4 s = *(const float4*)&sp[base + c0];
  float4 e = *(const float4*)&ed[base + c0];
  int kt = c0 >> 7, cw = c0 & 127, fk = cw >> 4, l0 = cw & 15;
  u16* o = dst + base + kt*128 + fk;
  o[(l0+0)*8] = f2bf((s.x+e.x)*LOG2E);
  o[(l0+1)*8] = f2bf((s.y+e.y)*LOG2E);
  o[(l0+2)*8] = f2bf((s.z+e.z)*LOG2E);
  o[(l0+3)*8] = f2bf((s.w+e.w)*LOG2E);
}

// qkvb[0:1536)=0, qkvb[1536+i]=bv[i]
__global__ void build_qkvb(float* __restrict__ qkvb, const float* __restrict__ bv){
  int i = blockIdx.x * blockDim.x + threadIdx.x;
  if (i < 2304) qkvb[i] = (i < 1536) ? 0.f : bv[i - 1536];
}

// ---------------------------------------------------------------------------
// LayerNorm: one wave per row, produce h1 (g1,be1) and h2 (g2,be2) in bf16
__global__ __launch_bounds__(256) void ln_kernel(
    const float* __restrict__ x,
    const float* __restrict__ g1, const float* __restrict__ be1,
    const float* __restrict__ g2, const float* __restrict__ be2,
    u16* __restrict__ h1, u16* __restrict__ h2){
  const int lane = threadIdx.x & 63, wave = threadIdx.x >> 6;
  const int row = blockIdx.x * 4 + wave;
  const float4* xr = (const float4*)(x + (size_t)row * 768);
  float4 v[3];
  float sum = 0.f, sq = 0.f;
  #pragma unroll
  for (int c = 0; c < 3; c++){
    v[c] = xr[lane + 64*c];
    sum += v[c].x + v[c].y + v[c].z + v[c].w;
    sq  += v[c].x*v[c].x + v[c].y*v[c].y + v[c].z*v[c].z + v[c].w*v[c].w;
  }
  #pragma unroll
  for (int d = 1; d < 64; d <<= 1){ sum += __shfl_xor(sum, d); sq += __shfl_xor(sq, d); }
  float mu  = sum * (1.f/768.f);
  float var = sq * (1.f/768.f) - mu*mu;
  float rs  = rsqrtf(var + 1e-5f);
  #pragma unroll
  for (int c = 0; c < 3; c++){
    int f4 = lane + 64*c;
    float4 ga = ((const float4*)g1)[f4], ba = ((const float4*)be1)[f4];
    float4 gb = ((const float4*)g2)[f4], bb = ((const float4*)be2)[f4];
    float nx = (v[c].x-mu)*rs, ny = (v[c].y-mu)*rs, nz = (v[c].z-mu)*rs, nw = (v[c].w-mu)*rs;
    ushort4 o1{f2bf(nx*ga.x+ba.x), f2bf(ny*ga.y+ba.y), f2bf(nz*ga.z+ba.z), f2bf(nw*ga.w+ba.w)};
    ushort4 o2{f2bf(nx*gb.x+bb.x), f2bf(ny*gb.y+bb.y), f2bf(nz*gb.z+bb.z), f2bf(nw*gb.w+bb.w)};
    ((ushort4*)(h1 + (size_t)row*768))[f4] = o1;
    ((ushort4*)(h2 + (size_t)row*768))[f4] = o2;
  }
}

// ---------------------------------------------------------------------------
// GEMM: C[M,N] = A[M,K](bf16) @ Bt[N,K](bf16)^T, fp32 accum.
// BK=64, XOR-swizzled LDS, XCD-aware block swizzle, 2-phase ping-pong
// with STATIC buffer indices (unroll-by-2; nt must be even, guarded anyway).
// EPI 0: +bias -> bf16            EPI 2: +bias, gelu -> bf16
// EPI 3: +bias +resid(f32) -> bf16   EPI 4: +bias +resid(bf16) -> f32
template<int EPI>
__global__ __launch_bounds__(256, 2) void gemm_bt(
    const u16* __restrict__ A, const u16* __restrict__ Bt, void* __restrict__ Cout,
    const float* __restrict__ bias, const void* __restrict__ resid,
    int M, int Nn, int K){
  __shared__ __align__(16) u16 As0[128*64];
  __shared__ __align__(16) u16 Bs0[128*64];
  __shared__ __align__(16) u16 As1[128*64];
  __shared__ __align__(16) u16 Bs1[128*64];
  const int tid = threadIdx.x, lane = tid & 63, wave = tid >> 6;
  const int wm = wave >> 1, wn = wave & 1;
  const int l15 = lane & 15, lg = lane >> 4;
  // XCD-aware swizzle: consecutive remapped blocks share the A-panel
  const int bid = blockIdx.y * gridDim.x + blockIdx.x;
  const int cpx = (gridDim.x * gridDim.y) >> 3;
  const int swz = (bid & 7) * cpx + (bid >> 3);
  const int m0 = (swz / gridDim.x) * 128, n0 = (swz % gridDim.x) * 128;

#define STAGE(Ad, Bd, k0) do { \
    _Pragma("unroll") \
    for (int i_ = 0; i_ < 4; i_++){ \
      int chunk_ = i_*256 + tid; \
      int row_ = chunk_ >> 3, seg_ = (chunk_ & 7) ^ (row_ & 7); \
      __builtin_amdgcn_global_load_lds( \
        (const __attribute__((address_space(1))) void*)&A[(size_t)(m0+row_)*K + (k0) + seg_*8], \
        (__attribute__((address_space(3))) void*)&Ad[(size_t)(i_*256 + wave*64)*8], 16, 0, 0); \
      __builtin_amdgcn_global_load_lds( \
        (const __attribute__((address_space(1))) void*)&Bt[(size_t)(n0+row_)*K + (k0) + seg_*8], \
        (__attribute__((address_space(3))) void*)&Bd[(size_t)(i_*256 + wave*64)*8], 16, 0, 0); \
    } } while(0)

#define COMPUTE(Ac, Bc) do { \
    bf16x8 af[4][2], bfr[4][2]; \
    _Pragma("unroll") \
    for (int i = 0; i < 4; i++){ \
      int ra = wm*64 + i*16 + l15, rb = wn*64 + i*16 + l15; \
      _Pragma("unroll") \
      for (int kk = 0; kk < 2; kk++){ \
        af[i][kk]  = *(const bf16x8*)&Ac[ra*64 + (((kk*4 + lg) ^ (l15 & 7)) << 3)]; \
        bfr[i][kk] = *(const bf16x8*)&Bc[rb*64 + (((kk*4 + lg) ^ (l15 & 7)) << 3)]; \
      } \
    } \
    _Pragma("unroll") \
    for (int kk = 0; kk < 2; kk++) \
      _Pragma("unroll") \
      for (int i = 0; i < 4; i++) \
        _Pragma("unroll") \
        for (int j = 0; j < 4; j++) \
          acc[i][j] = __builtin_amdgcn_mfma_f32_16x16x32_bf16(af[i][kk], bfr[j][kk], acc[i][j], 0, 0, 0); \
    } while(0)

  f32x4 acc[4][4] = {};
  const int nt = K >> 6;               // 12 or 48 here (even)
  STAGE(As0, Bs0, 0);
  for (int t = 0; t < nt; t += 2){
    __syncthreads();                   // drains STAGE(buf0): buf0 ready
    if (t + 1 < nt) STAGE(As1, Bs1, (t+1) << 6);
    COMPUTE(As0, Bs0);
    __syncthreads();                   // drains STAGE(buf1): buf1 ready
    if (t + 2 < nt) STAGE(As0, Bs0, (t+2) << 6);
    if (t + 1 < nt) COMPUTE(As1, Bs1);
  }
#undef STAGE
#undef COMPUTE
  #pragma unroll
  for (int i = 0; i < 4; i++){
    int row_base = m0 + wm*64 + i*16 + lg*4;
    #pragma unroll
    for (int j = 0; j < 4; j++){
      int col = n0 + wn*64 + j*16 + l15;
      float bb = bias ? bias[col] : 0.f;
      #pragma unroll
      for (int r = 0; r < 4; r++){
        size_t idx = (size_t)(row_base + r) * Nn + col;
        float v = acc[i][j][r] + bb;
        if (EPI == 3){
          v += ((const float*)resid)[idx];
          ((u16*)Cout)[idx] = f2bf(v);
        } else if (EPI == 4){
          v += bf2f(((const u16*)resid)[idx]);
          ((float*)Cout)[idx] = v;
        } else if (EPI == 2){
          float u = v + 0.044715f * v * v * v;
          float e = exp2f(-2.3022182f * u);          // exp(-1.5957691*u)
          ((u16*)Cout)[idx] = f2bf(v * __builtin_amdgcn_rcpf(1.f + e));
        } else {
          ((u16*)Cout)[idx] = f2bf(v);
        }
      }
    }
  }
}

// ---------------------------------------------------------------------------
// qkv v-part -> VT [B,H,64,512] via LDS tile transpose.
// Column index XOR-swizzled within each 128-col tile (chunk ^= hd&7).
__global__ void vtrans(const u16* __restrict__ qkv, u16* __restrict__ VTg){
  __shared__ u16 t[32][33];
  int bh = blockIdx.z, b = bh / 12, h = bh % 12;
  int n0 = blockIdx.x * 32, hd0 = blockIdx.y * 32;
  int tx = threadIdx.x, ty = threadIdx.y;
  #pragma unroll
  for (int i = 0; i < 4; i++){
    int n = n0 + ty + i*8;
    t[ty + i*8][tx] = qkv[((size_t)(b*512 + n))*2304 + 1536 + h*64 + hd0 + tx];
  }
  __syncthreads();
  #pragma unroll
  for (int i = 0; i < 4; i++){
    int hd = hd0 + ty + i*8;
    int col = n0 + tx;
    int tile = col >> 7, within = col & 127;
    int newcol = (tile << 7) + ((((within >> 3) ^ (hd & 7)) << 3)) + (within & 7);
    VTg[((size_t)bh*64 + hd)*512 + newcol] = t[tx][ty + i*8];
  }
}

// ---------------------------------------------------------------------------
// Attention: block = (q-tile 128) x (b,h); 4 waves, each 32 q-rows.
// K/V LDS-staged per block per kt; bf16 bias; unshifted exp2 softmax.
__global__ __launch_bounds__(256, 2) void attn_kernel(
    const u16* __restrict__ qkv, const u16* __restrict__ VTg,
    const u16* __restrict__ biasPb, u16* __restrict__ Og){
  __shared__ __align__(16) u16 Ks[128*64];
  __shared__ __align__(16) u16 Vs[64*128];
  __shared__ __align__(16) u16 Pl[4*32*136];
  const int tid = threadIdx.x, lane = tid & 63, wave = tid >> 6;
  const int l15 = lane & 15, lg = lane >> 4;
  // XCD swizzle: 4 consecutive remapped blocks share (b,h) K/V
  const int bid = blockIdx.y * 4 + blockIdx.x;           // nwg = 768
  const int swz = (bid & 7) * 96 + (bid >> 3);
  const int bh = swz >> 2, b = bh / 12, h = bh % 12;
  const int q0 = (swz & 3) * 128 + wave * 32;
  const u16* Qb = qkv + (size_t)b * 512 * 2304 + h * 64;   // row stride 2304
  const u16* Kb = Qb + 768;
  const u16* Vbh = VTg + (size_t)bh * 64 * 512;
  u16* Pw = &Pl[wave * 32 * 136];

  bf16x8 qf[2][2];
  #pragma unroll
  for (int fm = 0; fm < 2; fm++)
    #pragma unroll
    for (int kk = 0; kk < 2; kk++)
      qf[fm][kk] = *(const bf16x8*)&Qb[(size_t)(q0 + fm*16 + l15)*2304 + kk*32 + lg*8];

  f32x4 O[2][4] = {};
  float lrow[2][4] = {};

  for (int kt = 0; kt < 4; kt++){
    const int k0 = kt * 128;
    // bias: one bf16x8 per (fm,r)
    bf16x8 bb[2][4];
    #pragma unroll
    for (int fm = 0; fm < 2; fm++)
      #pragma unroll
      for (int r = 0; r < 4; r++){
        int qrow = q0 + fm*16 + lg*4 + r;
        bb[fm][r] = *(const bf16x8*)&biasPb[((size_t)(b*512 + qrow)*4 + kt)*128 + l15*8];
      }
    // stage K tile [128][64] (inverse-swizzled source, linear dest)
    #pragma unroll
    for (int i = 0; i < 4; i++){
      int chunk = i*256 + tid;
      int r = chunk >> 3, cc = chunk & 7;
      __builtin_amdgcn_global_load_lds(
        (const __attribute__((address_space(1))) void*)&Kb[(size_t)(k0 + r)*2304 + ((cc ^ (r & 7)) << 3)],
        (__attribute__((address_space(3))) void*)&Ks[(size_t)(i*256 + wave*64)*8],
        16, 0, 0);
    }
    // stage V tile [64][128] from pre-swizzled VTg (linear copy)
    #pragma unroll
    for (int i = 0; i < 4; i++){
      int chunk = i*256 + tid;
      int r = chunk >> 4, cc = chunk & 15;
      __builtin_amdgcn_global_load_lds(
        (const __attribute__((address_space(1))) void*)&Vbh[(size_t)r*512 + k0 + (cc << 3)],
        (__attribute__((address_space(3))) void*)&Vs[(size_t)(i*256 + wave*64)*8],
        16, 0, 0);
    }
    __syncthreads();

    // QK^T from LDS (swizzled reads)
    f32x4 S[2][8] = {};
    #pragma unroll
    for (int fk = 0; fk < 8; fk++)
      #pragma unroll
      for (int kk = 0; kk < 2; kk++){
        int row = fk*16 + l15;
        bf16x8 kf = *(const bf16x8*)&Ks[row*64 + (((kk*4 + lg) ^ (l15 & 7)) << 3)];
        S[0][fk] = __builtin_amdgcn_mfma_f32_16x16x32_bf16(qf[0][kk], kf, S[0][fk], 0,0,0);
        S[1][fk] = __builtin_amdgcn_mfma_f32_16x16x32_bf16(qf[1][kk], kf, S[1][fk], 0,0,0);
      }
    // p = exp2(qk' + bias'); row sums (no shift needed: args bounded, f32 accum)
    #pragma unroll
    for (int fm = 0; fm < 2; fm++)
      #pragma unroll
      for (int r = 0; r < 4; r++){
        float rs = 0.f;
        #pragma unroll
        for (int fk = 0; fk < 8; fk++){
          float p = exp2f(S[fm][fk][r] + (float)bb[fm][r][fk]);
          S[fm][fk][r] = p;
          rs += p;
        }
        rs += __shfl_xor(rs, 1); rs += __shfl_xor(rs, 2);
        rs += __shfl_xor(rs, 4); rs += __shfl_xor(rs, 8);
        lrow[fm][r] += rs;
      }
    // P -> LDS (per-wave private; intra-wave ordering, no extra barrier)
    #pragma unroll
    for (int fm = 0; fm < 2; fm++)
      #pragma unroll
      for (int fk = 0; fk < 8; fk++)
        #pragma unroll
        for (int r = 0; r < 4; r++)
          Pw[(fm*16 + lg*4 + r)*136 + fk*16 + l15] = f2bf(S[fm][fk][r]);
    bf16x8 pf[2][4];
    #pragma unroll
    for (int fm = 0; fm < 2; fm++)
      #pragma unroll
      for (int kk = 0; kk < 4; kk++)
        pf[fm][kk] = *(const bf16x8*)&Pw[(fm*16 + l15)*136 + kk*32 + lg*8];
    // PV from LDS V (swizzled reads)
    #pragma unroll
    for (int fn = 0; fn < 4; fn++)
      #pragma unroll
      for (int kk = 0; kk < 4; kk++){
        int row = fn*16 + l15;
        bf16x8 vf = *(const bf16x8*)&Vs[row*128 + (((kk*4 + lg) ^ (l15 & 7)) << 3)];
        O[0][fn] = __builtin_amdgcn_mfma_f32_16x16x32_bf16(pf[0][kk], vf, O[0][fn], 0,0,0);
        O[1][fn] = __builtin_amdgcn_mfma_f32_16x16x32_bf16(pf[1][kk], vf, O[1][fn], 0,0,0);
      }
    __syncthreads();   // all waves done with Ks/Vs before next stage
  }
  #pragma unroll
  for (int fm = 0; fm < 2; fm++)
    #pragma unroll
    for (int r = 0; r < 4; r++){
      float inv = __builtin_amdgcn_rcpf(lrow[fm][r]);
      int qrow = q0 + fm*16 + lg*4 + r;
      #pragma unroll
      for (int fn = 0; fn < 4; fn++)
        Og[((size_t)b*512 + qrow)*768 + h*64 + fn*16 + l15] = f2bf(O[fm][fn][r] * inv);
    }
}

// ---------------------------------------------------------------------------
extern "C" void kernel_launch(void* const* d_in, const int* in_sizes, int n_in,
                              void* d_out, int out_size, void* d_ws, size_t ws_size,
                              hipStream_t stream){
  const float* x   = (const float*)d_in[0];
  const float* sp  = (const float*)d_in[1];
  const float* ed  = (const float*)d_in[2];
  const float* Wq  = (const float*)d_in[3];
  const float* Wk  = (const float*)d_in[4];
  const float* Wv  = (const float*)d_in[5];
  const float* bv  = (const float*)d_in[6];
  const float* Wo  = (const float*)d_in[7];
  const float* bo  = (const float*)d_in[8];
  const float* g1  = (const float*)d_in[9];
  const float* be1 = (const float*)d_in[10];
  const float* g2  = (const float*)d_in[11];
  const float* be2 = (const float*)d_in[12];
  const float* W1  = (const float*)d_in[13];
  const float* bf1 = (const float*)d_in[14];
  const float* W2  = (const float*)d_in[15];
  const float* bf2 = (const float*)d_in[16];

  char* w = (char*)d_ws;
  size_t off = 0;
  auto alloc = [&](size_t bytes)->void*{ void* p = w + off; off += (bytes + 255) & ~(size_t)255; return p; };
  u16*   Gg    = (u16*)  alloc(8192ull*3072*2);   // FFN1 out; first 37.7MB double as qkv
  u16*   qkv   = Gg;                               // [8192][2304] bf16 (dead before FFN1)
  u16*   VTg   = (u16*)  alloc(8192ull*768*2);
  u16*   h1    = (u16*)  alloc(8192ull*768*2);
  u16*   h2    = (u16*)  alloc(8192ull*768*2);
  u16*   Og    = (u16*)  alloc(8192ull*768*2);
  u16*   attb  = (u16*)  alloc(8192ull*768*2);    // bf16 att residual
  u16*   biasPb= (u16*)  alloc(16ull*512*512*2);
  u16*   WqkvT = (u16*)  alloc(2304ull*768*2);
  u16*   WoT   = (u16*)  alloc(768ull*768*2);
  u16*   W1T   = (u16*)  alloc(3072ull*768*2);
  u16*   W2T   = (u16*)  alloc(768ull*3072*2);
  float* qkvb  = (float*)alloc(2304ull*4);

  const float qscale = 0.03608439182435161f * LOG2E;  // D^-0.5 * log2e folded into Wq

  // --- prep ---
  tpose_cast<<<dim3(24,24),dim3(32,8),0,stream>>>(WqkvT,            Wq, 768, 768, qscale);
  tpose_cast<<<dim3(24,24),dim3(32,8),0,stream>>>(WqkvT + 768*768,  Wk, 768, 768, 1.f);
  tpose_cast<<<dim3(24,24),dim3(32,8),0,stream>>>(WqkvT + 1536*768, Wv, 768, 768, 1.f);
  tpose_cast<<<dim3(24,24),dim3(32,8),0,stream>>>(WoT,              Wo, 768, 768, 1.f);
  tpose_cast<<<dim3(96,24),dim3(32,8),0,stream>>>(W1T, W1, 768, 3072, 1.f);
  tpose_cast<<<dim3(24,96),dim3(32,8),0,stream>>>(W2T, W2, 3072, 768, 1.f);
  bias_prep<<<4096,256,0,stream>>>(biasPb, sp, ed);
  build_qkvb<<<9,256,0,stream>>>(qkvb, bv);

  // --- layer norms (shared stats) ---
  ln_kernel<<<2048,256,0,stream>>>(x, g1, be1, g2, be2, h1, h2);

  // --- qkv projection ---
  gemm_bt<0><<<dim3(18,64),256,0,stream>>>(h1, WqkvT, qkv, qkvb, nullptr, 8192, 2304, 768);
  vtrans<<<dim3(16,2,192),dim3(32,8),0,stream>>>(qkv, VTg);

  // --- attention ---
  attn_kernel<<<dim3(4,192),256,0,stream>>>(qkv, VTg, biasPb, Og);

  // --- output projection + residual x -> bf16 att ---
  gemm_bt<3><<<dim3(6,64),256,0,stream>>>(Og, WoT, attb, bo, x, 8192, 768, 768);

  // --- FFN ---
  gemm_bt<2><<<dim3(24,64),256,0,stream>>>(h2, W1T, Gg, bf1, nullptr, 8192, 3072, 768);
  gemm_bt<4><<<dim3(6,64),256,0,stream>>>(Gg, W2T, (float*)d_out, bf2, attb, 8192, 768, 3072);
}